// Round 10
// baseline (134.691 us; speedup 1.0000x reference)
//
#include <hip/hip_runtime.h>
#include <hip/hip_bf16.h>

// B=8, NH=8, KS=VS=64, HW=1024, C=1536, GROUPS=24. pair = b*8+h (64 pairs).
// gn_partial (stats) -> attn_fused (GN affine-folded flash attn, K-range split
// across 2 blocks; un-normalized wv-scaled partial O + l to ws) -> merge.
// attn block: 256 thr = 4 waves, 128 q, 8 K-tiles, ~100 VGPR (5 waves/SIMD
// regime) + 32 KB LDS -> 4 blocks/CU co-resident (grid 1024 = 4/CU).
// K and V staged RAW (pack2 cast only). K's GN affine folded into Q frags
// (Q' = wk*Qn) + per-q softmax offset; V's weight folded into Opart writes,
// V's bias exported via bvtab and applied in merge (exact: softmax has fixed
// offset, so the split-K merge is linear).
// NOTE: __launch_bounds__ 2nd arg MUST be 2: arg>=4 clamps VGPR to 64 ->
// catastrophic spill (rounds 5/6, 400+ MB scratch traffic).

typedef __attribute__((ext_vector_type(8))) short bf16x8;
typedef __attribute__((ext_vector_type(4))) float f32x4;
typedef __attribute__((ext_vector_type(16))) float f32x16;
typedef unsigned short u16;
typedef unsigned int u32;

#define SM_SCALE 0.18033688f   // 0.125 * log2(e)
#define SM_OFF   8.0f          // fixed softmax offset (shift-invariant)

__device__ __forceinline__ u32 pack2(float a, float b) {  // (bf(b)<<16)|bf(a)
    union { float f; u32 u; } ua, ub; ua.f = a; ub.f = b;
    return __builtin_amdgcn_perm(ub.u + 0x8000u, ua.u + 0x8000u, 0x07060302u);
}
union BB { uint4 u; bf16x8 v; };

__device__ __forceinline__ float fexp2(float x) {   // single v_exp_f32
#if __has_builtin(__builtin_amdgcn_exp2f)
    return __builtin_amdgcn_exp2f(x);
#else
    float r; asm("v_exp_f32 %0, %1" : "=v"(r) : "v"(x)); return r;
#endif
}

__device__ __forceinline__ f32x16 zero16() {
    f32x16 z;
#pragma unroll
    for (int i = 0; i < 16; ++i) z[i] = 0.f;
    return z;
}

// v_permlane32_swap_b32(a, b): a.upper ⇄ b.lower.
//   ret0 = {lane<32: own a,            lane>=32: b from lane-32}
//   ret1 = {lane<32: a from lane+32,   lane>=32: own b}
__device__ __forceinline__ void swap32(u32 a, u32 b, int hi, u32& ret0, u32& ret1) {
#if __has_builtin(__builtin_amdgcn_permlane32_swap)
    (void)hi;
    auto sw = __builtin_amdgcn_permlane32_swap(a, b, false, false);
    ret0 = sw[0]; ret1 = sw[1];
#else
    u32 pa = __shfl_xor(a, 32), pb = __shfl_xor(b, 32);
    ret0 = hi ? pb : a;
    ret1 = hi ? b : pa;
#endif
}

// ---- Kernel 1: partial GN stats. 1536 blocks = 8 channel-octet slices per
// (b,group); partials[blk*2 + {0,1}] = {sum, sumsq} of 8192 floats.
__global__ __launch_bounds__(256) void gn_partial(const float* __restrict__ x,
                                                  float* __restrict__ partials) {
    int blk = blockIdx.x;
    const float4* p = (const float4*)(x + (size_t)blk * 8192);
    int t = threadIdx.x;
    float s1a = 0.f, s2a = 0.f, s1b = 0.f, s2b = 0.f;
#pragma unroll
    for (int i = 0; i < 8; i += 2) {
        float4 va = p[t + i * 256];
        float4 vb = p[t + (i + 1) * 256];
        s1a += va.x + va.y + va.z + va.w;
        s2a += va.x*va.x + va.y*va.y + va.z*va.z + va.w*va.w;
        s1b += vb.x + vb.y + vb.z + vb.w;
        s2b += vb.x*vb.x + vb.y*vb.y + vb.z*vb.z + vb.w*vb.w;
    }
    float s1 = s1a + s1b, s2 = s2a + s2b;
    for (int off = 32; off > 0; off >>= 1) {
        s1 += __shfl_down(s1, off);
        s2 += __shfl_down(s2, off);
    }
    __shared__ float a1[4], a2[4];
    int wave = t >> 6, lane = t & 63;
    if (lane == 0) { a1[wave] = s1; a2[wave] = s2; }
    __syncthreads();
    if (t == 0) {
        partials[blk * 2 + 0] = a1[0] + a1[1] + a1[2] + a1[3];
        partials[blk * 2 + 1] = a2[0] + a2[1] + a2[2] + a2[3];
    }
}

__device__ __forceinline__ void group_stats(const float* __restrict__ partials,
                                            int bg, float& mean, float& rstd) {
    float s1 = 0.f, s2 = 0.f;
#pragma unroll
    for (int j = 0; j < 8; ++j) {
        s1 += partials[(bg * 8 + j) * 2 + 0];
        s2 += partials[(bg * 8 + j) * 2 + 1];
    }
    mean = s1 * (1.f / 65536.f);
    float var = s2 * (1.f / 65536.f) - mean * mean;
    rstd = rsqrtf(var + 1e-5f);
}

// ---- Kernel 2: fused flash-attention, affine-folded GN, K-split over blocks.
// Grid 1024: bid = (ha*8 + qt)*64 + pair -> bid%8 = pair%8 (XCD-local reads).
// Block = 256 thr = 4 waves; 128 q (32/wave), K-tiles ha*8 .. ha*8+7.
__global__ __launch_bounds__(256, 2) void attn_fused(
    const float* __restrict__ x, const float* __restrict__ gamma,
    const float* __restrict__ beta, const float* __restrict__ partials,
    float* __restrict__ Opart, float* __restrict__ lpart,
    float* __restrict__ bvtab)
{
    const int bid = blockIdx.x;
    const int pair = bid & 63;
    const int qh = bid >> 6;        // 0..15
    const int qt = qh & 7;          // q-tile 0..7
    const int ha = qh >> 3;         // K-half 0/1: tiles ha*8 .. ha*8+7
    const int b = pair >> 3, h = pair & 7;
    const float* xb = x + (size_t)b * 1536 * 1024;
    const int tid = threadIdx.x;
    const int w2 = tid >> 6;
    const int lane = tid & 63;
    const int li = lane & 31;       // q within wave tile
    const int hi = lane >> 5;

    float ms[3], rs[3];
    group_stats(partials, b * 24 + 3 * h + 0, ms[0], rs[0]);
    group_stats(partials, b * 24 + 3 * h + 1, ms[1], rs[1]);
    group_stats(partials, b * 24 + 3 * h + 2, ms[2], rs[2]);

    __shared__ uint4 KT[2][512];            // [buf][row*8 + (chunk^(row&7))]
    __shared__ uint4 VT[2][512];

    // ---- staging geometry (raw x -> bf16 tiles, no per-tile affine)
    const int sr = tid & 63;                // K row (key) / V channel
    const int cc0 = tid >> 6;               // 0..3
    const int kx = sr & 7;
    const int kidx0 = sr * 8 + (cc0 ^ kx);
    const int kidx1 = sr * 8 + ((cc0 + 4) ^ kx);
    const int vidx0 = sr * 8 + ((cc0 * 2) ^ kx);
    const int vidx1 = sr * 8 + ((cc0 * 2 + 1) ^ kx);

    const float* kbase = xb + (size_t)(h * 192) * 1024 + sr;          // + c*1024 + kt*64
    const float* vbase = xb + (size_t)(h * 192 + 128 + sr) * 1024 + cc0 * 16; // + kt*64

    // ---- Q: normalize, fold K's weight (Q' = wk*Qn) + dq = sum_c bk_c*Qn_c.
    // B-frag B[n=q=li][k=c = cs*16+hi*8+j].
    const int q0 = qt * 128 + w2 * 32;
    bf16x8 bq[4];
    float dqp = 0.f;
#pragma unroll
    for (int cs = 0; cs < 4; ++cs) {
        u32 qq[4];
#pragma unroll
        for (int jp = 0; jp < 4; ++jp) {
            int c0 = cs * 16 + hi * 8 + jp * 2;     // shared contraction channel
            int cgq = h * 192 + 64 + c0;
            int cgk = h * 192 + c0;
            float wq0 = gamma[cgq] * rs[1],     bq0 = beta[cgq] - ms[1] * wq0;
            float wq1 = gamma[cgq + 1] * rs[1], bq1 = beta[cgq + 1] - ms[1] * wq1;
            float wk0 = gamma[cgk] * rs[0],     bk0 = beta[cgk] - ms[0] * wk0;
            float wk1 = gamma[cgk + 1] * rs[0], bk1 = beta[cgk + 1] - ms[0] * wk1;
            float a0 = xb[(size_t)cgq * 1024 + q0 + li];
            float a1 = xb[(size_t)(cgq + 1) * 1024 + q0 + li];
            float qn0 = __builtin_fmaf(a0, wq0, bq0);
            float qn1 = __builtin_fmaf(a1, wq1, bq1);
            dqp = __builtin_fmaf(bk0, qn0, dqp);
            dqp = __builtin_fmaf(bk1, qn1, dqp);
            qq[jp] = pack2(qn0 * wk0, qn1 * wk1);
        }
        BB tb; tb.u = uint4{qq[0], qq[1], qq[2], qq[3]};
        bq[cs] = tb.v;
    }
    const float dq = dqp + __shfl_xor(dqp, 32);     // partner holds other 32 ch
    const float offq = __builtin_fmaf(dq, SM_SCALE, -SM_OFF);

    f32x16 oacc[2];
    oacc[0] = zero16(); oacc[1] = zero16();
    float lsum = 0.f;

    const int x7 = li & 7;                  // (row&7) for MFMA-side LDS reads

    // ---- staging load (raw f32 -> regs) and commit (pack2 + ds_write only)
    float rk[16], rv[16];
#define LOAD_TILE(KT_)                                                        \
    {                                                                         \
        const float* kp = kbase + (KT_) * 64;                                 \
        _Pragma("unroll")                                                     \
        for (int u = 0; u < 16; ++u) {                                        \
            int c = ((u < 8) ? cc0 : (cc0 + 4)) * 8 + (u & 7);                \
            rk[u] = kp[(size_t)c * 1024];                                     \
        }                                                                     \
        const float* vp = vbase + (KT_) * 64;                                 \
        _Pragma("unroll")                                                     \
        for (int f = 0; f < 4; ++f) {                                         \
            float4 vq = *(const float4*)(vp + f * 4);                         \
            rv[f * 4 + 0] = vq.x; rv[f * 4 + 1] = vq.y;                       \
            rv[f * 4 + 2] = vq.z; rv[f * 4 + 3] = vq.w;                       \
        }                                                                     \
    }
#define COMMIT_TILE(BUF_)                                                     \
    {                                                                         \
        uint4 ka, kc, va, vc;                                                 \
        ka.x = pack2(rk[0], rk[1]);   ka.y = pack2(rk[2], rk[3]);             \
        ka.z = pack2(rk[4], rk[5]);   ka.w = pack2(rk[6], rk[7]);             \
        kc.x = pack2(rk[8], rk[9]);   kc.y = pack2(rk[10], rk[11]);           \
        kc.z = pack2(rk[12], rk[13]); kc.w = pack2(rk[14], rk[15]);           \
        va.x = pack2(rv[0], rv[1]);   va.y = pack2(rv[2], rv[3]);             \
        va.z = pack2(rv[4], rv[5]);   va.w = pack2(rv[6], rv[7]);             \
        vc.x = pack2(rv[8], rv[9]);   vc.y = pack2(rv[10], rv[11]);           \
        vc.z = pack2(rv[12], rv[13]); vc.w = pack2(rv[14], rv[15]);           \
        KT[BUF_][kidx0] = ka; KT[BUF_][kidx1] = kc;                           \
        VT[BUF_][vidx0] = va; VT[BUF_][vidx1] = vc;                           \
    }

    // ---- prologue: stage this half's tile 0
    LOAD_TILE(ha * 8);
    COMMIT_TILE(0);
    __syncthreads();

#pragma unroll 2
    for (int kt8 = 0; kt8 < 8; ++kt8) {
        const int cur = kt8 & 1;
        // ---- issue next tile's raw loads (covered by this tile's compute)
        if (kt8 < 7) LOAD_TILE(ha * 8 + kt8 + 1);

        // ---- per 32-key block: S^T = K_raw Q'^T, then softmax+pack
        BB pbv[4];
#pragma unroll
        for (int kf = 0; kf < 2; ++kf) {
            bf16x8 ak[4];
#pragma unroll
            for (int cs = 0; cs < 4; ++cs)
                ak[cs] = ((const BB*)&KT[cur][(kf * 32 + li) * 8 + ((cs * 2 + hi) ^ x7)])->v;
            f32x16 acc = zero16();
            __builtin_amdgcn_s_setprio(1);
#pragma unroll
            for (int cs = 0; cs < 4; ++cs)
                acc = __builtin_amdgcn_mfma_f32_32x32x16_bf16(ak[cs], bq[cs], acc, 0, 0, 0);
            __builtin_amdgcn_s_setprio(0);
            // P = exp2(fma(S_raw, scale, offq)); pack + partner swap.
#pragma unroll
            for (int s = 0; s < 2; ++s) {
                float p0 = fexp2(__builtin_fmaf(acc[8 * s + 0], SM_SCALE, offq));
                float p1 = fexp2(__builtin_fmaf(acc[8 * s + 1], SM_SCALE, offq));
                float p2 = fexp2(__builtin_fmaf(acc[8 * s + 2], SM_SCALE, offq));
                float p3 = fexp2(__builtin_fmaf(acc[8 * s + 3], SM_SCALE, offq));
                float p4 = fexp2(__builtin_fmaf(acc[8 * s + 4], SM_SCALE, offq));
                float p5 = fexp2(__builtin_fmaf(acc[8 * s + 5], SM_SCALE, offq));
                float p6 = fexp2(__builtin_fmaf(acc[8 * s + 6], SM_SCALE, offq));
                float p7 = fexp2(__builtin_fmaf(acc[8 * s + 7], SM_SCALE, offq));
                lsum += ((p0 + p1) + (p2 + p3)) + ((p4 + p5) + (p6 + p7));
                u32 Pa = pack2(p0, p1), Pb = pack2(p2, p3);
                u32 Pc = pack2(p4, p5), Pd = pack2(p6, p7);
                u32 w0, w1, w2m, w3;
                swap32(Pa, Pc, hi, w0, w2m);  // w0=offs 8hi+{0,1}, w2m=8hi+{4,5}
                swap32(Pb, Pd, hi, w1, w3);   // w1=offs 8hi+{2,3}, w3=8hi+{6,7}
                pbv[kf * 2 + s].u = uint4{w0, w1, w2m, w3};
            }
        }

        // ---- O_raw^T += V_raw P : A=V[m=v][k=key] (2 vf x 4 ks), B=P
#pragma unroll
        for (int vf = 0; vf < 2; ++vf) {
            bf16x8 av[4];
#pragma unroll
            for (int ks = 0; ks < 4; ++ks)
                av[ks] = ((const BB*)&VT[cur][(vf * 32 + li) * 8 + ((ks * 2 + hi) ^ x7)])->v;
            __builtin_amdgcn_s_setprio(1);
#pragma unroll
            for (int ks = 0; ks < 4; ++ks)
                oacc[vf] = __builtin_amdgcn_mfma_f32_32x32x16_bf16(av[ks], pbv[ks].v, oacc[vf], 0, 0, 0);
            __builtin_amdgcn_s_setprio(0);
        }

        // ---- commit staged tile (pack2+ds_write), one barrier per iteration
        if (kt8 < 7) COMMIT_TILE(cur ^ 1);
        __syncthreads();
    }

    // ---- epilogue: write wv-scaled un-normalized partial O + per-q l.
    lsum += __shfl_xor(lsum, 32);
    float* ob = Opart + (size_t)(ha * 64 + pair) * 65536 + q0 + li;
#pragma unroll
    for (int vf = 0; vf < 2; ++vf)
#pragma unroll
        for (int r = 0; r < 16; ++r) {
            int v = vf * 32 + (r & 3) + 8 * (r >> 2) + 4 * hi;
            float wv = gamma[h * 192 + 128 + v] * rs[2];
            ob[(size_t)v * 1024] = oacc[vf][r] * wv;
        }
    if (hi == 0)
        lpart[(size_t)(ha * 64 + pair) * 1024 + q0 + li] = lsum;
    // bv table (all ha==0 blocks write identical values; benign race)
    if (ha == 0 && tid < 64) {
        int cgv = h * 192 + 128 + tid;
        float wv = gamma[cgv] * rs[2];
        bvtab[pair * 64 + tid] = beta[cgv] - ms[2] * wv;
    }
}

// ---- Kernel 3: merge K-halves: out = (O0+O1)/(l0+l1) + bv[v].
// 512 blocks x 256 thr; 8 float4/thread. out[pair][v][q]; v const per float4.
__global__ __launch_bounds__(256) void merge_halves(
    const float* __restrict__ Opart, const float* __restrict__ lpart,
    const float* __restrict__ bvtab, float* __restrict__ out)
{
#pragma unroll
    for (int i = 0; i < 8; ++i) {
        int idx4 = blockIdx.x * 2048 + i * 256 + threadIdx.x;
        size_t f = (size_t)idx4 * 4;
        int pair = (int)(f >> 16);
        int rem = (int)(f & 65535);
        int q = rem & 1023;
        int v = rem >> 10;
        float4 a = *(const float4*)(Opart + (size_t)pair * 65536 + rem);
        float4 b2 = *(const float4*)(Opart + (size_t)(64 + pair) * 65536 + rem);
        float4 la = *(const float4*)(lpart + (size_t)pair * 1024 + q);
        float4 lb = *(const float4*)(lpart + (size_t)(64 + pair) * 1024 + q);
        float bvv = bvtab[pair * 64 + v];
        float4 o;
        o.x = (a.x + b2.x) / (la.x + lb.x) + bvv;
        o.y = (a.y + b2.y) / (la.y + lb.y) + bvv;
        o.z = (a.z + b2.z) / (la.z + lb.z) + bvv;
        o.w = (a.w + b2.w) / (la.w + lb.w) + bvv;
        *(float4*)(out + f) = o;
    }
}

extern "C" void kernel_launch(void* const* d_in, const int* in_sizes, int n_in,
                              void* d_out, int out_size, void* d_ws, size_t ws_size,
                              hipStream_t stream) {
    const float* x     = (const float*)d_in[0];
    const float* gamma = (const float*)d_in[1];
    const float* beta  = (const float*)d_in[2];
    float* out = (float*)d_out;

    float* partials = (float*)d_ws;                       // 3072 f32 (12 KB)
    float* Opart = (float*)((char*)d_ws + 32768);         // 2*64*65536 f32 = 33.5 MB
    float* lpart = Opart + (size_t)2 * 64 * 65536;        // 2*64*1024 f32 = 512 KB
    float* bvtab = lpart + (size_t)2 * 64 * 1024;         // 64*64 f32 = 16 KB

    gn_partial<<<1536, 256, 0, stream>>>(x, partials);
    attn_fused<<<1024, 256, 0, stream>>>(x, gamma, beta, partials, Opart, lpart, bvtab);
    merge_halves<<<512, 256, 0, stream>>>(Opart, lpart, bvtab, out);
}

// Round 11
// 116.947 us; speedup vs baseline: 1.1517x; 1.1517x over previous
//
#include <hip/hip_runtime.h>
#include <hip/hip_bf16.h>

// B=8, NH=8, KS=VS=64, HW=1024, C=1536, GROUPS=24. pair = b*8+h (64 pairs).
// gn_partial (stats) -> attn_fused (GN affine-folded flash attention):
//   Grid 256 = 4 q-tiles x 64 pairs; block = 512 thr = 8 q-waves (32 q each,
//   256 q/block) SHARING one double-buffered K/V tile stream -> chip-wide
//   staging and x re-reads HALVED vs 128-q blocks. All 16 K-tiles per block,
//   no split-K, no merge. K and V staged RAW (pack2 cast only); K's GN
//   affine folded into Q frags (Q' = wk*Qn) + per-q softmax offset; V's
//   affine applied in the epilogue: out = wv*(O_raw/l) + bv (exact, linear).
//   32x32x16 MFMA; P in-register via permlane32_swap; XOR-swizzled LDS
//   (even-spread ds accesses); prefetch-early/commit-late; 1 barrier/tile.
// NOTE: __launch_bounds__ 2nd arg MUST be 2: arg>=4 clamps VGPR to 64 ->
// catastrophic spill (rounds 5/6, 400+ MB scratch traffic).

typedef __attribute__((ext_vector_type(8))) short bf16x8;
typedef __attribute__((ext_vector_type(4))) float f32x4;
typedef __attribute__((ext_vector_type(16))) float f32x16;
typedef unsigned short u16;
typedef unsigned int u32;

#define SM_SCALE 0.18033688f   // 0.125 * log2(e)
#define SM_OFF   8.0f          // fixed softmax offset (shift-invariant)

__device__ __forceinline__ u32 pack2(float a, float b) {  // (bf(b)<<16)|bf(a)
    union { float f; u32 u; } ua, ub; ua.f = a; ub.f = b;
    return __builtin_amdgcn_perm(ub.u + 0x8000u, ua.u + 0x8000u, 0x07060302u);
}
union BB { uint4 u; bf16x8 v; };

__device__ __forceinline__ float fexp2(float x) {   // single v_exp_f32
#if __has_builtin(__builtin_amdgcn_exp2f)
    return __builtin_amdgcn_exp2f(x);
#else
    float r; asm("v_exp_f32 %0, %1" : "=v"(r) : "v"(x)); return r;
#endif
}

__device__ __forceinline__ f32x16 zero16() {
    f32x16 z;
#pragma unroll
    for (int i = 0; i < 16; ++i) z[i] = 0.f;
    return z;
}

// v_permlane32_swap_b32(a, b): a.upper ⇄ b.lower.
//   ret0 = {lane<32: own a,            lane>=32: b from lane-32}
//   ret1 = {lane<32: a from lane+32,   lane>=32: own b}
__device__ __forceinline__ void swap32(u32 a, u32 b, int hi, u32& ret0, u32& ret1) {
#if __has_builtin(__builtin_amdgcn_permlane32_swap)
    (void)hi;
    auto sw = __builtin_amdgcn_permlane32_swap(a, b, false, false);
    ret0 = sw[0]; ret1 = sw[1];
#else
    u32 pa = __shfl_xor(a, 32), pb = __shfl_xor(b, 32);
    ret0 = hi ? pb : a;
    ret1 = hi ? b : pa;
#endif
}

// ---- Kernel 1: partial GN stats. 1536 blocks = 8 channel-octet slices per
// (b,group); partials[blk*2 + {0,1}] = {sum, sumsq} of 8192 floats.
__global__ __launch_bounds__(256) void gn_partial(const float* __restrict__ x,
                                                  float* __restrict__ partials) {
    int blk = blockIdx.x;
    const float4* p = (const float4*)(x + (size_t)blk * 8192);
    int t = threadIdx.x;
    float s1a = 0.f, s2a = 0.f, s1b = 0.f, s2b = 0.f;
#pragma unroll
    for (int i = 0; i < 8; i += 2) {
        float4 va = p[t + i * 256];
        float4 vb = p[t + (i + 1) * 256];
        s1a += va.x + va.y + va.z + va.w;
        s2a += va.x*va.x + va.y*va.y + va.z*va.z + va.w*va.w;
        s1b += vb.x + vb.y + vb.z + vb.w;
        s2b += vb.x*vb.x + vb.y*vb.y + vb.z*vb.z + vb.w*vb.w;
    }
    float s1 = s1a + s1b, s2 = s2a + s2b;
    for (int off = 32; off > 0; off >>= 1) {
        s1 += __shfl_down(s1, off);
        s2 += __shfl_down(s2, off);
    }
    __shared__ float a1[4], a2[4];
    int wave = t >> 6, lane = t & 63;
    if (lane == 0) { a1[wave] = s1; a2[wave] = s2; }
    __syncthreads();
    if (t == 0) {
        partials[blk * 2 + 0] = a1[0] + a1[1] + a1[2] + a1[3];
        partials[blk * 2 + 1] = a2[0] + a2[1] + a2[2] + a2[3];
    }
}

__device__ __forceinline__ void group_stats(const float* __restrict__ partials,
                                            int bg, float& mean, float& rstd) {
    float s1 = 0.f, s2 = 0.f;
#pragma unroll
    for (int j = 0; j < 8; ++j) {
        s1 += partials[(bg * 8 + j) * 2 + 0];
        s2 += partials[(bg * 8 + j) * 2 + 1];
    }
    mean = s1 * (1.f / 65536.f);
    float var = s2 * (1.f / 65536.f) - mean * mean;
    rstd = rsqrtf(var + 1e-5f);
}

// ---- Kernel 2: fused flash-attention, affine-folded GN, 256-q blocks.
// Grid 256: bid = qt*64 + pair -> bid%8 = pair%8 (XCD-local x re-reads).
// Block = 512 thr = 8 waves; wave w owns q0 = qt*256 + w*32 .. +31.
// Staging (512 thr share one tile): K: thread (sr=tid&63, kcc=tid>>6) loads
// 8 channels kcc*8..+7 at s=kt*64+sr (256B segments/wave) -> 1 uint4.
// V: thread (vc=tid>>3, vs8=(tid&7)*8) loads 8 s at channel vc (256B
// segments) -> 1 uint4. Both written XOR-swizzled (chunk^(row&7)).
__global__ __launch_bounds__(512, 2) void attn_fused(
    const float* __restrict__ x, const float* __restrict__ gamma,
    const float* __restrict__ beta, const float* __restrict__ partials,
    float* __restrict__ out)
{
    const int bid = blockIdx.x;
    const int qt = bid >> 6;        // 0..3
    const int pair = bid & 63;
    const int b = pair >> 3, h = pair & 7;
    const float* xb = x + (size_t)b * 1536 * 1024;
    const int tid = threadIdx.x;
    const int w2 = tid >> 6;        // wave 0..7
    const int lane = tid & 63;
    const int li = lane & 31;       // q within wave tile
    const int hi = lane >> 5;

    float ms[3], rs[3];
    group_stats(partials, b * 24 + 3 * h + 0, ms[0], rs[0]);
    group_stats(partials, b * 24 + 3 * h + 1, ms[1], rs[1]);
    group_stats(partials, b * 24 + 3 * h + 2, ms[2], rs[2]);

    __shared__ uint4 KT[2][512];            // [buf][row*8 + (chunk^(row&7))]
    __shared__ uint4 VT[2][512];

    // ---- staging geometry (raw x -> bf16 tiles, no per-tile affine)
    const int sr  = tid & 63;               // K key row
    const int kcc = tid >> 6;               // 0..7 channel-octet
    const int kidx = sr * 8 + (kcc ^ (sr & 7));
    const int vc  = tid >> 3;               // 0..63 V channel
    const int vs8 = (tid & 7) * 8;          // s-octet within tile
    const int vidx = vc * 8 + ((tid & 7) ^ (vc & 7));

    const float* kbase = xb + (size_t)(h * 192 + kcc * 8) * 1024 + sr;  // + u*1024 + kt*64
    const float* vbase = xb + (size_t)(h * 192 + 128 + vc) * 1024 + vs8; // + kt*64

    // ---- Q: normalize, fold K's weight (Q' = wk*Qn) + dq = sum_c bk_c*Qn_c.
    // B-frag B[n=q=li][k=c = cs*16+hi*8+j].
    const int q0 = qt * 256 + w2 * 32;
    bf16x8 bq[4];
    float dqp = 0.f;
#pragma unroll
    for (int cs = 0; cs < 4; ++cs) {
        u32 qq[4];
#pragma unroll
        for (int jp = 0; jp < 4; ++jp) {
            int c0 = cs * 16 + hi * 8 + jp * 2;     // shared contraction channel
            int cgq = h * 192 + 64 + c0;
            int cgk = h * 192 + c0;
            float wq0 = gamma[cgq] * rs[1],     bq0 = beta[cgq] - ms[1] * wq0;
            float wq1 = gamma[cgq + 1] * rs[1], bq1 = beta[cgq + 1] - ms[1] * wq1;
            float wk0 = gamma[cgk] * rs[0],     bk0 = beta[cgk] - ms[0] * wk0;
            float wk1 = gamma[cgk + 1] * rs[0], bk1 = beta[cgk + 1] - ms[0] * wk1;
            float a0 = xb[(size_t)cgq * 1024 + q0 + li];
            float a1 = xb[(size_t)(cgq + 1) * 1024 + q0 + li];
            float qn0 = __builtin_fmaf(a0, wq0, bq0);
            float qn1 = __builtin_fmaf(a1, wq1, bq1);
            dqp = __builtin_fmaf(bk0, qn0, dqp);
            dqp = __builtin_fmaf(bk1, qn1, dqp);
            qq[jp] = pack2(qn0 * wk0, qn1 * wk1);
        }
        BB tb; tb.u = uint4{qq[0], qq[1], qq[2], qq[3]};
        bq[cs] = tb.v;
    }
    const float dq = dqp + __shfl_xor(dqp, 32);     // partner holds other 32 ch
    const float offq = __builtin_fmaf(dq, SM_SCALE, -SM_OFF);

    f32x16 oacc[2];
    oacc[0] = zero16(); oacc[1] = zero16();
    float lsum = 0.f;

    const int x7 = li & 7;                  // (row&7) for MFMA-side LDS reads

    // ---- staging load (raw f32 -> regs) and commit (pack2 + ds_write only)
    float rk[8], rv[8];
#define LOAD_TILE(KT_)                                                        \
    {                                                                         \
        const float* kp = kbase + (KT_) * 64;                                 \
        _Pragma("unroll")                                                     \
        for (int u = 0; u < 8; ++u) rk[u] = kp[(size_t)u * 1024];             \
        const float* vp = vbase + (KT_) * 64;                                 \
        float4 v0 = *(const float4*)(vp);                                     \
        float4 v1 = *(const float4*)(vp + 4);                                 \
        rv[0] = v0.x; rv[1] = v0.y; rv[2] = v0.z; rv[3] = v0.w;               \
        rv[4] = v1.x; rv[5] = v1.y; rv[6] = v1.z; rv[7] = v1.w;               \
    }
#define COMMIT_TILE(BUF_)                                                     \
    {                                                                         \
        uint4 ka, va;                                                         \
        ka.x = pack2(rk[0], rk[1]); ka.y = pack2(rk[2], rk[3]);               \
        ka.z = pack2(rk[4], rk[5]); ka.w = pack2(rk[6], rk[7]);               \
        va.x = pack2(rv[0], rv[1]); va.y = pack2(rv[2], rv[3]);               \
        va.z = pack2(rv[4], rv[5]); va.w = pack2(rv[6], rv[7]);               \
        KT[BUF_][kidx] = ka; VT[BUF_][vidx] = va;                             \
    }

    // ---- prologue: stage tile 0
    LOAD_TILE(0);
    COMMIT_TILE(0);
    __syncthreads();

#pragma unroll 2
    for (int kt = 0; kt < 16; ++kt) {
        const int cur = kt & 1;
        // ---- issue next tile's raw loads (covered by this tile's compute)
        if (kt < 15) LOAD_TILE(kt + 1);

        // ---- per 32-key block: S^T = K_raw Q'^T, then softmax+pack
        BB pbv[4];
#pragma unroll
        for (int kf = 0; kf < 2; ++kf) {
            bf16x8 ak[4];
#pragma unroll
            for (int cs = 0; cs < 4; ++cs)
                ak[cs] = ((const BB*)&KT[cur][(kf * 32 + li) * 8 + ((cs * 2 + hi) ^ x7)])->v;
            f32x16 acc = zero16();
            __builtin_amdgcn_s_setprio(1);
#pragma unroll
            for (int cs = 0; cs < 4; ++cs)
                acc = __builtin_amdgcn_mfma_f32_32x32x16_bf16(ak[cs], bq[cs], acc, 0, 0, 0);
            __builtin_amdgcn_s_setprio(0);
            // P = exp2(fma(S_raw, scale, offq)); pack + partner swap.
#pragma unroll
            for (int s = 0; s < 2; ++s) {
                float p0 = fexp2(__builtin_fmaf(acc[8 * s + 0], SM_SCALE, offq));
                float p1 = fexp2(__builtin_fmaf(acc[8 * s + 1], SM_SCALE, offq));
                float p2 = fexp2(__builtin_fmaf(acc[8 * s + 2], SM_SCALE, offq));
                float p3 = fexp2(__builtin_fmaf(acc[8 * s + 3], SM_SCALE, offq));
                float p4 = fexp2(__builtin_fmaf(acc[8 * s + 4], SM_SCALE, offq));
                float p5 = fexp2(__builtin_fmaf(acc[8 * s + 5], SM_SCALE, offq));
                float p6 = fexp2(__builtin_fmaf(acc[8 * s + 6], SM_SCALE, offq));
                float p7 = fexp2(__builtin_fmaf(acc[8 * s + 7], SM_SCALE, offq));
                lsum += ((p0 + p1) + (p2 + p3)) + ((p4 + p5) + (p6 + p7));
                u32 Pa = pack2(p0, p1), Pb = pack2(p2, p3);
                u32 Pc = pack2(p4, p5), Pd = pack2(p6, p7);
                u32 w0, w1, w2m, w3;
                swap32(Pa, Pc, hi, w0, w2m);  // w0=offs 8hi+{0,1}, w2m=8hi+{4,5}
                swap32(Pb, Pd, hi, w1, w3);   // w1=offs 8hi+{2,3}, w3=8hi+{6,7}
                pbv[kf * 2 + s].u = uint4{w0, w1, w2m, w3};
            }
        }

        // ---- O_raw^T += V_raw P : A=V[m=v][k=key] (2 vf x 4 ks), B=P
#pragma unroll
        for (int vf = 0; vf < 2; ++vf) {
            bf16x8 av[4];
#pragma unroll
            for (int ks = 0; ks < 4; ++ks)
                av[ks] = ((const BB*)&VT[cur][(vf * 32 + li) * 8 + ((ks * 2 + hi) ^ x7)])->v;
            __builtin_amdgcn_s_setprio(1);
#pragma unroll
            for (int ks = 0; ks < 4; ++ks)
                oacc[vf] = __builtin_amdgcn_mfma_f32_32x32x16_bf16(av[ks], pbv[ks].v, oacc[vf], 0, 0, 0);
            __builtin_amdgcn_s_setprio(0);
        }

        // ---- commit staged tile (pack2+ds_write), one barrier per iteration
        if (kt < 15) COMMIT_TILE(cur ^ 1);
        __syncthreads();
    }

    // ---- epilogue: l reduce, V-affine fold: out = wv*(O_raw/l) + bv.
    lsum += __shfl_xor(lsum, 32);
    float invl = 1.f / lsum;
    float* ob = out + (size_t)pair * 65536 + q0 + li;
#pragma unroll
    for (int vf = 0; vf < 2; ++vf)
#pragma unroll
        for (int r = 0; r < 16; ++r) {
            int v = vf * 32 + (r & 3) + 8 * (r >> 2) + 4 * hi;
            int cgv = h * 192 + 128 + v;
            float wv = gamma[cgv] * rs[2];
            float bvv = beta[cgv] - ms[2] * wv;
            ob[(size_t)v * 1024] = __builtin_fmaf(oacc[vf][r] * invl, wv, bvv);
        }
}

extern "C" void kernel_launch(void* const* d_in, const int* in_sizes, int n_in,
                              void* d_out, int out_size, void* d_ws, size_t ws_size,
                              hipStream_t stream) {
    const float* x     = (const float*)d_in[0];
    const float* gamma = (const float*)d_in[1];
    const float* beta  = (const float*)d_in[2];
    float* out = (float*)d_out;

    float* partials = (float*)d_ws;                       // 3072 f32

    gn_partial<<<1536, 256, 0, stream>>>(x, partials);
    attn_fused<<<256, 512, 0, stream>>>(x, gamma, beta, partials, out);
}